// Round 12
// baseline (3312.409 us; speedup 1.0000x reference)
//
#include <hip/hip_runtime.h>
#include <hip/hip_bf16.h>
#include <stdint.h>

#define DI __device__ __forceinline__

typedef __attribute__((ext_vector_type(4))) float f32x4;
typedef __attribute__((ext_vector_type(8))) short bf16x8;   // 8 bf16 = 4 VGPR (MFMA A/B frag)
typedef __attribute__((ext_vector_type(4))) short s16x4;

typedef unsigned short ushort_t;

constexpr int M_ = 16384;   // B*T
constexpr int N_ = 4096;    // OUT
constexpr int K_ = 4096;    // IN
constexpr int R_ = 64;

// big-tile GEMM geometry
constexpr int BM = 256, BN = 256, BK = 64;
constexpr int NSEG = 3;
constexpr int NT_SEG = K_ / BK;          // 64 K-tiles per segment
constexpr int TOT_T = NSEG * NT_SEG;     // 192 total K-tiles (even; NIT = 96)

// ---------- bf16 split helpers ----------
DI ushort_t f32_to_bf16_rne(float f) {
    unsigned u = __builtin_bit_cast(unsigned, f);
    u += 0x7FFFu + ((u >> 16) & 1u);           // round-nearest-even
    return (ushort_t)(u >> 16);
}
DI float bf16_to_f32(ushort_t h) {
    return __builtin_bit_cast(float, (unsigned)h << 16);
}

DI void async_cp16(const void* g, void* l) {
    __builtin_amdgcn_global_load_lds(
        (const __attribute__((address_space(1))) unsigned*)g,
        (__attribute__((address_space(3))) unsigned*)l, 16, 0, 0);
}

// barrier with compiler memory fences (the asm clobbers pin all memory ops
// to their phase region; s_barrier alone is not a compiler fence)
DI void bar_() {
    asm volatile("" ::: "memory");
    __builtin_amdgcn_s_barrier();
    asm volatile("" ::: "memory");
}
// phase mid-point. DRAIN=true: r7 baseline (hard lgkmcnt(0) drain + sched pin).
// DRAIN=false: H1 test — compiler inserts its own counted lgkmcnt(N) before
// each consuming MFMA (plain loads; rule #18 applies only to asm reads).
template <bool DRAIN>
DI void mid_() {
    bar_();
    if constexpr (DRAIN) {
        asm volatile("s_waitcnt lgkmcnt(0)" ::: "memory");
        __builtin_amdgcn_sched_barrier(0);
    }
    __builtin_amdgcn_s_setprio(1);
}
DI void endp_() { __builtin_amdgcn_s_setprio(0); bar_(); }

// ---------- prep 1: W = weight_main + (U*S) @ V  ->  planar hiW, loW (bf16) ----------
__global__ __launch_bounds__(256) void k_fuse_w(const float* __restrict__ WM,
                                                const float* __restrict__ U,
                                                const float* __restrict__ S,
                                                const float* __restrict__ V,
                                                ushort_t* __restrict__ hiW,
                                                ushort_t* __restrict__ loW) {
    __shared__ __align__(16) float sUS[64][68];    // padded rows
    __shared__ __align__(16) float sV[64][128];
    int t = threadIdx.x;
    int n0 = (blockIdx.x >> 5) * 64;
    int k0 = (blockIdx.x & 31) * 128;
#pragma unroll
    for (int j = 0; j < 4; ++j) {                  // US tile 64x64, folded on load
        int f = j * 1024 + t * 4;
        int r = f >> 6, c = f & 63;
        f32x4 uu = *(const f32x4*)&U[(size_t)(n0 + r) * R_ + c];
        f32x4 ss = *(const f32x4*)&S[c];
        *(f32x4*)&sUS[r][c] = uu * ss;
    }
#pragma unroll
    for (int j = 0; j < 8; ++j) {                  // V tile 64x128
        int f = j * 1024 + t * 4;
        int r = f >> 7, c = f & 127;
        *(f32x4*)&sV[r][c] = *(const f32x4*)&V[(size_t)r * K_ + k0 + c];
    }
    __syncthreads();
    int tn = t >> 5;
    int tk = t & 31;
    float acc[8][4] = {};
    for (int r = 0; r < R_; ++r) {
        f32x4 vv = *(const f32x4*)&sV[r][tk * 4];
#pragma unroll
        for (int a = 0; a < 8; ++a) {
            float u = sUS[tn * 8 + a][r];
#pragma unroll
            for (int c = 0; c < 4; ++c) acc[a][c] += u * vv[c];
        }
    }
#pragma unroll
    for (int a = 0; a < 8; ++a) {
        int n = n0 + tn * 8 + a;
        int k = k0 + tk * 4;
        f32x4 wmv = *(const f32x4*)&WM[(size_t)n * K_ + k];
        s16x4 h4, l4;
#pragma unroll
        for (int c = 0; c < 4; ++c) {
            float w = wmv[c] + acc[a][c];
            ushort_t h = f32_to_bf16_rne(w);
            h4[c] = (short)h;
            l4[c] = (short)f32_to_bf16_rne(w - bf16_to_f32(h));
        }
        *(s16x4*)&hiW[(size_t)n * K_ + k] = h4;
        *(s16x4*)&loW[(size_t)n * K_ + k] = l4;
    }
}

// ---------- prep 2: x -> planar hiA, loA (bf16) ----------
__global__ __launch_bounds__(256) void k_split_x(const float* __restrict__ X,
                                                 ushort_t* __restrict__ hiA,
                                                 ushort_t* __restrict__ loA) {
    size_t i = ((size_t)blockIdx.x * 256 + threadIdx.x) * 8;
    f32x4 a = *(const f32x4*)&X[i];
    f32x4 b = *(const f32x4*)&X[i + 4];
    bf16x8 h, l;
#pragma unroll
    for (int j = 0; j < 4; ++j) {
        ushort_t ha = f32_to_bf16_rne(a[j]);
        ushort_t hb = f32_to_bf16_rne(b[j]);
        h[j]     = (short)ha;
        h[4 + j] = (short)hb;
        l[j]     = (short)f32_to_bf16_rne(a[j] - bf16_to_f32(ha));
        l[4 + j] = (short)f32_to_bf16_rne(b[j] - bf16_to_f32(hb));
    }
    *(bf16x8*)&hiA[i] = h;
    *(bf16x8*)&loA[i] = l;
}

// ---------- main GEMM: 256x256, BK=64, 8 waves, 8-phase + register-prefetch ----------
// out = hiA@hiW^T + loA@hiW^T + hiA@loW^T + bias  (3 planar bf16 segments)
// Template A/B: DRAIN=true == the twice-benched r7 kernel; DRAIN=false == H1 test.
// Both instantiations compute bit-identical outputs (same MFMA order).
// Stage schedule + vmcnt checkpoints (audited r5/r6) are DRAIN-independent:
//   ph1:A(to,0) ph2:A(to,1) ph3:B(ne,0) ph4:B(ne,1)+vmcnt(4)
//   ph5:A(ne,0) ph6:A(ne,1) ph7:B(no,0) ph8:B(no,1)+vmcnt(4)
// At ph4's vmcnt(4): steady-state outstanding = 12 -> drains B(to)+A(to) BEFORE
// the barrier; each wave verifies pre-barrier => post-barrier buf1 landed for all.
// No vmcnt(0) in the loop. Wrap-tile stages hit dead regions only.
template <bool DRAIN>
__global__ __launch_bounds__(512, 2) void k_gemm_8ph(const ushort_t* __restrict__ hiA,
                                                     const ushort_t* __restrict__ loA,
                                                     const ushort_t* __restrict__ hiW,
                                                     const ushort_t* __restrict__ loW,
                                                     const float* __restrict__ bias,
                                                     float* __restrict__ out) {
    __shared__ __align__(16) ushort_t lA[2][BM * BK];   // 2 x 32 KiB
    __shared__ __align__(16) ushort_t lB[2][BN * BK];   // 2 x 32 KiB  (128 KiB total)

    // XCD-bijective swizzle; grid = 1024 (divisible by 8)
    int bid = blockIdx.x;
    int wg  = (bid & 7) * (gridDim.x >> 3) + (bid >> 3);
    int m0  = (wg >> 4) * BM;
    int n0  = (wg & 15) * BN;

    int tid  = threadIdx.x;
    int lane = tid & 63;
    int w    = tid >> 6;
    int wr   = w >> 2;            // 0..1  (128 M-rows each)
    int wc   = w & 3;             // 0..3  (64 N-cols each)
    int fr   = lane & 15;
    int fq   = lane >> 4;

    f32x4 acc[8][4] = {};

    // stage one half-tile; chunk-XOR swizzle on the GLOBAL source (linear LDS dest)
    auto stageA = [&](int tau, int h) {
        int seg = tau >> 6;
        const ushort_t* As = (seg == 1) ? loA : hiA;
        int k0 = (tau & (NT_SEG - 1)) * BK;
        ushort_t* dst = &lA[tau & 1][h * (128 * 64)];
#pragma unroll
        for (int j = 0; j < 2; ++j) {
            int ci  = j * 512 + tid;          // 16B chunk id: row=ci>>3, chunk=ci&7
            int row = ci >> 3, pc = ci & 7;
            int lc  = pc ^ (row & 7);         // involution
            async_cp16(&As[(size_t)(m0 + h * 128 + row) * K_ + k0 + lc * 8], &dst[ci * 8]);
        }
    };
    auto stageB = [&](int tau, int h) {
        int seg = tau >> 6;
        const ushort_t* Bs = (seg == 2) ? loW : hiW;
        int k0 = (tau & (NT_SEG - 1)) * BK;
        ushort_t* dst = &lB[tau & 1][h * (128 * 64)];
#pragma unroll
        for (int j = 0; j < 2; ++j) {
            int ci  = j * 512 + tid;
            int row = ci >> 3, pc = ci & 7;
            int lc  = pc ^ (row & 7);
            async_cp16(&Bs[(size_t)(n0 + h * 128 + row) * K_ + k0 + lc * 8], &dst[ci * 8]);
        }
    };
    auto rdA = [&](const ushort_t* la, int i, int ks) -> bf16x8 {
        int row = wr * 128 + i * 16 + fr;
        return *(const bf16x8*)&la[row * 64 + (((ks * 4 + fq) ^ (row & 7)) << 3)];
    };
    auto rdB = [&](const ushort_t* lb, int j, int ks) -> bf16x8 {
        int row = wc * 64 + j * 16 + fr;
        return *(const bf16x8*)&lb[row * 64 + (((ks * 4 + fq) ^ (row & 7)) << 3)];
    };

    bf16x8 aX[4], aY[4], bX[4], bY[4];

#define RD_A(dst, la, ib, ks) do { \
    dst[0] = rdA(la, (ib) + 0, ks); dst[1] = rdA(la, (ib) + 1, ks); \
    dst[2] = rdA(la, (ib) + 2, ks); dst[3] = rdA(la, (ib) + 3, ks); } while (0)
#define RD_B(dst, lb, ks) do { \
    dst[0] = rdB(lb, 0, ks); dst[1] = rdB(lb, 1, ks); \
    dst[2] = rdB(lb, 2, ks); dst[3] = rdB(lb, 3, ks); } while (0)
#define MFMA16(IB, A_, B_) do { \
    _Pragma("unroll") \
    for (int i_ = 0; i_ < 4; ++i_) \
        _Pragma("unroll") \
        for (int j_ = 0; j_ < 4; ++j_) \
            acc[(IB) + i_][j_] = __builtin_amdgcn_mfma_f32_16x16x32_bf16( \
                A_[i_], B_[j_], acc[(IB) + i_][j_], 0, 0, 0); } while (0)

    const ushort_t* la0 = lA[0]; const ushort_t* lb0 = lB[0];
    const ushort_t* la1 = lA[1]; const ushort_t* lb1 = lB[1];

    // ---- prologue: tile0 (full) -> buf0; tile1 B-halves -> buf1; 12 loads
    stageB(0, 0); stageB(0, 1); stageA(0, 0); stageA(0, 1);
    stageB(1, 0); stageB(1, 1);
    asm volatile("s_waitcnt vmcnt(4)" ::: "memory");   // oldest 8 = tile0 landed
    bar_();
    RD_A(aX, la0, 0, 0); RD_B(bX, lb0, 0);             // pre-issue ph1's frags

    constexpr int NIT = TOT_T / 2;   // 96
    for (int it = 0; it < NIT; ++it) {
        int to = 2 * it + 1;                 // odd tile (buf1), computed ph5-8
        int ne = (2 * it + 2) % TOT_T;       // next even tile -> buf0
        int no = (2 * it + 3) % TOT_T;       // next odd tile  -> buf1

        // ---- ph1
        stageA(to, 0);
        mid_<DRAIN>();
        RD_A(aY, la0, 4, 0);
        MFMA16(0, aX, bX);
        endp_();
        // ---- ph2
        stageA(to, 1);
        mid_<DRAIN>();
        RD_A(aX, la0, 0, 1); RD_B(bY, lb0, 1);
        MFMA16(4, aY, bX);
        endp_();
        // ---- ph3
        stageB(ne, 0);
        mid_<DRAIN>();
        RD_A(aY, la0, 4, 1);
        MFMA16(0, aX, bY);
        endp_();
        // ---- ph4: vmcnt checkpoint for tile `to` BEFORE its first reads
        stageB(ne, 1);
        asm volatile("s_waitcnt vmcnt(4)" ::: "memory");
        mid_<DRAIN>();
        RD_A(aX, la1, 0, 0); RD_B(bX, lb1, 0);
        MFMA16(4, aY, bY);
        endp_();
        // ---- ph5
        stageA(ne, 0);
        mid_<DRAIN>();
        RD_A(aY, la1, 4, 0);
        MFMA16(0, aX, bX);
        endp_();
        // ---- ph6
        stageA(ne, 1);
        mid_<DRAIN>();
        RD_A(aX, la1, 0, 1); RD_B(bY, lb1, 1);
        MFMA16(4, aY, bX);
        endp_();
        // ---- ph7
        stageB(no, 0);
        mid_<DRAIN>();
        RD_A(aY, la1, 4, 1);
        MFMA16(0, aX, bY);
        endp_();
        // ---- ph8: vmcnt checkpoint for tile `ne` BEFORE its first reads
        stageB(no, 1);
        asm volatile("s_waitcnt vmcnt(4)" ::: "memory");
        mid_<DRAIN>();
        RD_A(aX, la0, 0, 0); RD_B(bX, lb0, 0);
        MFMA16(4, aY, bY);
        endp_();
    }

    asm volatile("s_waitcnt vmcnt(0)" ::: "memory");   // drain wrap stages

#undef RD_A
#undef RD_B
#undef MFMA16

    // epilogue: C/D layout col=lane&15, row=(lane>>4)*4+reg  [m89]
    float bcol[4];
#pragma unroll
    for (int j = 0; j < 4; ++j) bcol[j] = bias[n0 + wc * 64 + j * 16 + fr];
#pragma unroll
    for (int i = 0; i < 8; ++i) {
        int gm = m0 + wr * 128 + i * 16 + fq * 4;
#pragma unroll
        for (int j = 0; j < 4; ++j) {
            int gn = n0 + wc * 64 + j * 16 + fr;
#pragma unroll
            for (int r2 = 0; r2 < 4; ++r2)
                out[(size_t)(gm + r2) * N_ + gn] = acc[i][j][r2] + bcol[j];
        }
    }
}

// ---------- tier-2 GEMM (ws fits only W): 128x128 m97 structure, in-register x split ----------
__global__ __launch_bounds__(256, 2) void k_gemm_small(const float* __restrict__ X,
                                                       const ushort_t* __restrict__ hiW,
                                                       const ushort_t* __restrict__ loW,
                                                       const float* __restrict__ bias,
                                                       float* __restrict__ out) {
    __shared__ __align__(16) ushort_t lA[128 * 64];
    __shared__ __align__(16) ushort_t lB[128 * 64];
    int bid = blockIdx.x;
    int cpx = gridDim.x >> 3;
    int wg  = (bid & 7) * cpx + (bid >> 3);
    constexpr int NBN = N_ / 128;
    int m0 = (wg / NBN) * 128;
    int n0 = (wg % NBN) * 128;
    int tid  = threadIdx.x;
    int lane = tid & 63;
    int w    = tid >> 6;
    int wr   = w >> 1, wc = w & 1;
    int fr   = lane & 15;
    int fq   = lane >> 4;
    f32x4 acc[4][4] = {};
    for (int seg = 0; seg < 3; ++seg) {
        const ushort_t* Bs = (seg == 2) ? loW : hiW;
        bool wantLo = (seg == 1);
        for (int kt = 0; kt < K_ / 64; ++kt) {
            int k0 = kt * 64;
#pragma unroll
            for (int j = 0; j < 4; ++j) {
                int f = j * 2048 + tid * 8;
                int row = f >> 6, col = f & 63;
                async_cp16(&Bs[(size_t)(n0 + row) * K_ + k0 + col], &lB[f]);
            }
#pragma unroll
            for (int j = 0; j < 4; ++j) {
                int f = j * 2048 + tid * 8;
                int row = f >> 6, c = f & 63;
                const float* xp = &X[(size_t)(m0 + row) * K_ + k0 + c];
                f32x4 x0 = *(const f32x4*)xp;
                f32x4 x1 = *(const f32x4*)(xp + 4);
                bf16x8 o;
#pragma unroll
                for (int e = 0; e < 4; ++e) {
                    ushort_t h0 = f32_to_bf16_rne(x0[e]);
                    ushort_t h1 = f32_to_bf16_rne(x1[e]);
                    o[e]     = (short)(wantLo ? f32_to_bf16_rne(x0[e] - bf16_to_f32(h0)) : h0);
                    o[4 + e] = (short)(wantLo ? f32_to_bf16_rne(x1[e] - bf16_to_f32(h1)) : h1);
                }
                *(bf16x8*)&lA[f] = o;
            }
            __syncthreads();
#pragma unroll
            for (int ks = 0; ks < 2; ++ks) {
                bf16x8 af[4], bfv[4];
#pragma unroll
                for (int i = 0; i < 4; ++i) {
                    af[i]  = *(const bf16x8*)&lA[(wr * 64 + i * 16 + fr) * 64 + ks * 32 + fq * 8];
                    bfv[i] = *(const bf16x8*)&lB[(wc * 64 + i * 16 + fr) * 64 + ks * 32 + fq * 8];
                }
#pragma unroll
                for (int i = 0; i < 4; ++i)
#pragma unroll
                    for (int j = 0; j < 4; ++j)
                        acc[i][j] = __builtin_amdgcn_mfma_f32_16x16x32_bf16(af[i], bfv[j], acc[i][j], 0, 0, 0);
            }
            __syncthreads();
        }
    }
    float bcol[4];
#pragma unroll
    for (int j = 0; j < 4; ++j) bcol[j] = bias[n0 + wc * 64 + j * 16 + fr];
#pragma unroll
    for (int i = 0; i < 4; ++i) {
        int gm = m0 + wr * 64 + i * 16 + fq * 4;
#pragma unroll
        for (int j = 0; j < 4; ++j) {
            int gn = n0 + wc * 64 + j * 16 + fr;
#pragma unroll
            for (int r2 = 0; r2 < 4; ++r2)
                out[(size_t)(gm + r2) * N_ + gn] = acc[i][j][r2] + bcol[j];
        }
    }
}

// ---------- ws-free correct fallback (fp32 vector; insurance only) ----------
__global__ __launch_bounds__(256) void k_naive(const float* __restrict__ X,
                                               const float* __restrict__ WM,
                                               const float* __restrict__ U,
                                               const float* __restrict__ S,
                                               const float* __restrict__ V,
                                               const float* __restrict__ bias,
                                               float* __restrict__ out) {
    __shared__ __align__(16) float sX[64][68];
    __shared__ __align__(16) float sW[64][68];
    __shared__ __align__(16) float sV[64][68];
    int t = threadIdx.x;
    int m0 = (blockIdx.x >> 6) * 64;
    int n0 = (blockIdx.x & 63) * 64;
    int tm = t >> 4, tn = t & 15;
    float acc[4][4] = {}, pacc[4][4] = {};
    for (int kc = 0; kc < K_ / 64; ++kc) {
        __syncthreads();
#pragma unroll
        for (int j = 0; j < 4; ++j) {
            int f = j * 1024 + t * 4;
            int r = f >> 6, c = f & 63;
            *(f32x4*)&sX[r][c] = *(const f32x4*)&X[(size_t)(m0 + r) * K_ + kc * 64 + c];
            *(f32x4*)&sW[r][c] = *(const f32x4*)&WM[(size_t)(n0 + r) * K_ + kc * 64 + c];
            *(f32x4*)&sV[r][c] = *(const f32x4*)&V[(size_t)r * K_ + kc * 64 + c];
        }
        __syncthreads();
        for (int k4 = 0; k4 < 16; ++k4) {
            f32x4 xa[4], wb[4], vb[4];
#pragma unroll
            for (int a = 0; a < 4; ++a) xa[a] = *(const f32x4*)&sX[tm * 4 + a][k4 * 4];
#pragma unroll
            for (int b = 0; b < 4; ++b) {
                wb[b] = *(const f32x4*)&sW[tn * 4 + b][k4 * 4];
                vb[b] = *(const f32x4*)&sV[tn * 4 + b][k4 * 4];
            }
#pragma unroll
            for (int a = 0; a < 4; ++a)
#pragma unroll
                for (int b = 0; b < 4; ++b)
#pragma unroll
                    for (int e = 0; e < 4; ++e) {
                        acc[a][b]  += xa[a][e] * wb[b][e];
                        pacc[a][b] += xa[a][e] * vb[b][e];
                    }
        }
    }
    __syncthreads();
#pragma unroll
    for (int j = 0; j < 4; ++j) {
        int f = j * 1024 + t * 4;
        int nl = f >> 6, r = f & 63;
        f32x4 uu = *(const f32x4*)&U[(size_t)(n0 + nl) * R_ + r];
        f32x4 ss = *(const f32x4*)&S[r];
        f32x4 us = uu * ss;
        *(f32x4*)&sV[nl][r] = us;
    }
#pragma unroll
    for (int a = 0; a < 4; ++a)
#pragma unroll
        for (int b = 0; b < 4; ++b) sW[tm * 4 + a][tn * 4 + b] = pacc[a][b];
    __syncthreads();
#pragma unroll
    for (int a = 0; a < 4; ++a)
#pragma unroll
        for (int b = 0; b < 4; ++b) {
            float s2 = acc[a][b];
            for (int r = 0; r < R_; ++r) s2 += sW[tm * 4 + a][r] * sV[tn * 4 + b][r];
            out[(size_t)(m0 + tm * 4 + a) * N_ + n0 + tn * 4 + b] = s2 + bias[n0 + tn * 4 + b];
        }
}

extern "C" void kernel_launch(void* const* d_in, const int* in_sizes, int n_in,
                              void* d_out, int out_size, void* d_ws, size_t ws_size,
                              hipStream_t stream) {
    const float* x    = (const float*)d_in[0];
    const float* wm   = (const float*)d_in[1];
    const float* U    = (const float*)d_in[2];
    const float* S    = (const float*)d_in[3];
    const float* V    = (const float*)d_in[4];
    const float* bias = (const float*)d_in[5];
    float* out = (float*)d_out;

    const size_t szA = (size_t)M_ * K_ * 2;   // 128 MiB per planar x-split buffer
    const size_t szW = (size_t)N_ * K_ * 2;   //  32 MiB per planar W-split buffer

    if (ws_size >= 2 * szA + 2 * szW) {
        ushort_t* hiA = (ushort_t*)d_ws;
        ushort_t* loA = (ushort_t*)((char*)d_ws + szA);
        ushort_t* hiW = (ushort_t*)((char*)d_ws + 2 * szA);
        ushort_t* loW = (ushort_t*)((char*)d_ws + 2 * szA + szW);
        k_fuse_w<<<dim3((N_ / 64) * (K_ / 128)), dim3(256), 0, stream>>>(wm, U, S, V, hiW, loW);
        k_split_x<<<dim3(M_ * K_ / 2048), dim3(256), 0, stream>>>(x, hiA, loA);
        // Within-probe A/B (one acquisition, per-dispatch rocprof):
        //   dispatch 1 = DRAIN=true  (r7 baseline schedule, sanity anchor)
        //   dispatch 2 = DRAIN=false (H1 test). Outputs bit-identical.
        k_gemm_8ph<true><<<dim3((M_ / BM) * (N_ / BN)), dim3(512), 0, stream>>>(
            hiA, loA, hiW, loW, bias, out);
        k_gemm_8ph<false><<<dim3((M_ / BM) * (N_ / BN)), dim3(512), 0, stream>>>(
            hiA, loA, hiW, loW, bias, out);
    } else if (ws_size >= 2 * szW) {
        ushort_t* hiW = (ushort_t*)d_ws;
        ushort_t* loW = (ushort_t*)((char*)d_ws + szW);
        k_fuse_w<<<dim3((N_ / 64) * (K_ / 128)), dim3(256), 0, stream>>>(wm, U, S, V, hiW, loW);
        k_gemm_small<<<dim3((M_ / 128) * (N_ / 128)), dim3(256), 0, stream>>>(
            x, hiW, loW, bias, out);
    } else {
        k_naive<<<dim3((M_ / 64) * (N_ / 64)), dim3(256), 0, stream>>>(x, wm, U, S, V, bias, out);
    }
}